// Round 2
// 322.899 us; speedup vs baseline: 1.0264x; 1.0264x over previous
//
#include <hip/hip_runtime.h>
#include <stdint.h>

#define EPSV 1e-5f

typedef __attribute__((ext_vector_type(8))) short short8;
typedef __attribute__((ext_vector_type(4))) float floatx4;
typedef __attribute__((ext_vector_type(2))) float float2v;

__device__ __forceinline__ unsigned short f2bf(float f) {
    union { float f; uint32_t u; } v; v.f = f;
    uint32_t u = v.u;
    return (unsigned short)((u + 0x7FFFu + ((u >> 16) & 1u)) >> 16);  // RNE
}

// ---- kernel 1: depthwise 3x3 + BN1 + ReLU + exact fp32 prune -> y bf16 [b][c][n]
//      halo stride 60 floats (16B-aligned rows); interior stored at col 0,
//      cols 56..59 zeroed so halo[row*60 - 1] (= prev row col 59) is the left pad.
//      8-wide output groups: per row 1x b64 + 2x b128 + 1x b64 LDS reads.
//      b==0 blocks also fold BN2 into pw weights, PERMUTED for k_pw's K-slot
//      mapping: w_bf[o][s] = pw_w[o][c(s)], c(s) = (s>>5)*4 + ((s>>3)&3) + 16*(s&7).
__global__ __launch_bounds__(256) void k_dw(
        const float* __restrict__ x, const float* __restrict__ dw_w,
        const float* __restrict__ dw_b, const float* __restrict__ g1,
        const float* __restrict__ b1, const float* __restrict__ m1,
        const float* __restrict__ v1,
        const float* __restrict__ pw_w, const float* __restrict__ pw_b,
        const float* __restrict__ g2, const float* __restrict__ b2,
        const float* __restrict__ m2, const float* __restrict__ v2,
        unsigned short* __restrict__ y_ws,
        unsigned short* __restrict__ w_bf, float* __restrict__ bias2) {
    const int c = blockIdx.x, b = blockIdx.y;
    const int t = threadIdx.x;
    __shared__ __align__(16) float halo_buf[4 + 58 * 60];  // 4-float front pad
    __shared__ float red[4];
    float* halo = halo_buf + 4;

    if (b == 0) {   // fused weight-fold with K-slot permutation
        int idx = c * 256 + t;
        int o = idx >> 7, s = idx & 127;
        int csrc = ((s >> 5) << 2) + ((s >> 3) & 3) + ((s & 7) << 4);
        float inv = g2[o] / sqrtf(v2[o] + EPSV);
        w_bf[idx] = f2bf(pw_w[o * 128 + csrc] * inv);
        if (s == 0) bias2[o] = pw_b[o] * inv + b2[o] - m2[o] * inv;
    }

    const float* xs = x + (size_t)(b * 128 + c) * 3136;

    // border zeros: row 0 (15 f4), row 57 (15 f4), cols 56..59 rows 1..56 (56 f4),
    // and the 4-float front pad (serves halo[-1] for row 0).
    {
        floatx4 zz = {0.f, 0.f, 0.f, 0.f};
        if (t < 15)       *(floatx4*)(halo + 4 * t) = zz;                  // row 0
        else if (t < 30)  *(floatx4*)(halo + 57 * 60 + 4 * (t - 15)) = zz; // row 57
        else if (t < 86)  *(floatx4*)(halo + (t - 29) * 60 + 56) = zz;     // right pad
        else if (t == 86) *(floatx4*)halo_buf = zz;                        // front pad
    }
    // interior: 784 float4 loads -> single aligned b128 LDS writes
    {
        const floatx4* x4 = (const floatx4*)xs;
        #pragma unroll
        for (int i = 0; i < 4; ++i) {
            int f = t + 256 * i;
            if (f < 784) {
                floatx4 v = x4[f];
                int p = 4 * f;
                int h = p / 56, ww = p - h * 56;
                *(floatx4*)(halo + (h + 1) * 60 + ww) = v;   // 16B aligned
            }
        }
    }
    const float* wk = dw_w + c * 9;
    float k0 = wk[0], k1 = wk[1], k2 = wk[2], k3 = wk[3], k4 = wk[4],
          k5 = wk[5], k6 = wk[6], k7 = wk[7], k8 = wk[8];
    float inv1 = g1[c] / sqrtf(v1[c] + EPSV);                 // exact, matches ref
    float add0 = dw_b[c] * inv1 + b1[c] - m1[c] * inv1;
    __syncthreads();

    // 392 groups of 8 outputs (56 rows x 7 groups); thread t does g = t, t+256
    float yv[16];
    float mx = 0.f;
    #pragma unroll
    for (int gi = 0; gi < 2; ++gi) {
        int g = t + gi * 256;
        if (g < 392) {
            int gh = g / 7, gw = (g - gh * 7) * 8;
            const float* p0 = halo + gh * 60 + gw;
            float w0[10], w1[10], w2[10];
#define LOADROW(dst, p) { \
            float2v L_ = *(const float2v*)((p) - 2); \
            floatx4 M0_ = *(const floatx4*)(p); \
            floatx4 M1_ = *(const floatx4*)((p) + 4); \
            float2v R_ = *(const float2v*)((p) + 8); \
            dst[0] = L_[1]; \
            dst[1] = M0_[0]; dst[2] = M0_[1]; dst[3] = M0_[2]; dst[4] = M0_[3]; \
            dst[5] = M1_[0]; dst[6] = M1_[1]; dst[7] = M1_[2]; dst[8] = M1_[3]; \
            dst[9] = R_[0]; }
            LOADROW(w0, p0)
            LOADROW(w1, p0 + 60)
            LOADROW(w2, p0 + 120)
#undef LOADROW
            #pragma unroll
            for (int j = 0; j < 8; ++j) {
                float s = k0 * w0[j] + k1 * w0[j + 1] + k2 * w0[j + 2]
                        + k3 * w1[j] + k4 * w1[j + 1] + k5 * w1[j + 2]
                        + k6 * w2[j] + k7 * w2[j + 1] + k8 * w2[j + 2];
                float yy = fmaxf(s * inv1 + add0, 0.f);
                mx = fmaxf(mx, yy);
                yv[gi * 8 + j] = yy;
            }
        }
    }
    #pragma unroll
    for (int off = 32; off; off >>= 1) mx = fmaxf(mx, __shfl_xor(mx, off));
    if ((t & 63) == 0) red[t >> 6] = mx;
    __syncthreads();
    float m4 = fmaxf(fmaxf(red[0], red[1]), fmaxf(red[2], red[3]));
    float scale = (m4 >= 4.0f) ? 1.f : 0.f;   // DW_THR, exact fp32 decision

    unsigned short* yo = y_ws + (size_t)(b * 128 + c) * 3136;
    #pragma unroll
    for (int gi = 0; gi < 2; ++gi) {
        int g = t + gi * 256;
        if (g < 392) {
            uint4 pkv;
            uint32_t pk[4];
            #pragma unroll
            for (int j2 = 0; j2 < 4; ++j2) {
                unsigned short h0 = f2bf(yv[gi * 8 + 2 * j2] * scale);
                unsigned short h1 = f2bf(yv[gi * 8 + 2 * j2 + 1] * scale);
                pk[j2] = (uint32_t)h0 | ((uint32_t)h1 << 16);
            }
            pkv.x = pk[0]; pkv.y = pk[1]; pkv.z = pk[2]; pkv.w = pk[3];
            *(uint4*)(yo + g * 8) = pkv;       // 16B aligned, lanes contiguous
        }
    }
}

// ---- kernel 2: pointwise GEMM.
//      Staging: coalesced uint4 y loads (8c x 8n tile per thread), in-REGISTER
//      transpose (compile-time short extraction), 8x b128 LDS writes.
//      Layout: B_s[row n][slot'][e] with pitch 144 shorts (288B); slot' =
//      slot ^ (n>>3); slot s at row n holds c = (s ^ (n>>3)) + 16e.
//      K-slot c-permutation is matched by the permuted w_bf (A operand), so
//      MFMA pairs identical c on both operands. Writes conflict-free; reads
//      <=2-way per 8-lane group. 2 barriers; wave-private LDS epilogue.
__global__ __launch_bounds__(256, 2) void k_pw(
        const unsigned short* __restrict__ y,     // [b][c][3136] bf16
        const unsigned short* __restrict__ w_bf,  // [o][s] bf16, K-permuted
        const float* __restrict__ bias2, float* __restrict__ z) {
    const int nt = blockIdx.x;   // 25 N-tiles of 128 (last is half)
    const int b  = blockIdx.y;   // 64 batches
    const int t = threadIdx.x;
    const int w = t >> 6, lane = t & 63;
    const int q = lane >> 4, r = lane & 15;
    __shared__ __align__(16) char smem[36864];    // B_s (36.9KB) then reused as E
    short* B_s = (short*)smem;

    // A fragments: wave w owns o in [w*64, w*64+64); slot j of a[it][kk] holds
    // w[o][c = kk*4 + q + 16*j] (permuted w_bf)
    short8 a[4][4];
    #pragma unroll
    for (int it = 0; it < 4; ++it)
        #pragma unroll
        for (int kk = 0; kk < 4; ++kk)
            a[it][kk] = *(const short8*)(w_bf +
                (size_t)(w * 64 + it * 16 + r) * 128 + kk * 32 + q * 8);

    // stage: thread t loads y[c = t>>4 + 16i][nb..nb+8), nb=(t&15)*8 (coalesced),
    // register-transposes to W[j] = {y[t>>4 + 16e][nb+j]}, writes b128.
    {
        const int n0g = nt * 128;
        const int nb = (t & 15) * 8;
        const bool valid = (n0g + nb < 3136);      // chunks fully valid or out
        uint32_t Vd[8][4];
        const unsigned short* yb = y + (size_t)(b * 128) * 3136 + n0g + nb;
        #pragma unroll
        for (int i = 0; i < 8; ++i) {
            int cc = (t >> 4) + i * 16;
            uint4 v = make_uint4(0u, 0u, 0u, 0u);
            if (valid) v = *(const uint4*)(yb + (size_t)cc * 3136);
            Vd[i][0] = v.x; Vd[i][1] = v.y; Vd[i][2] = v.z; Vd[i][3] = v.w;
        }
        const int slot_w = (t >> 4) ^ (t & 15);    // ^ (n>>3), n>>3 == t&15
        #pragma unroll
        for (int j = 0; j < 8; ++j) {
            const int sh = (j & 1) * 16;
            uint32_t Wd[4];
            #pragma unroll
            for (int k2 = 0; k2 < 4; ++k2) {
                uint32_t lo = (Vd[2 * k2][j >> 1] >> sh) & 0xffffu;
                uint32_t hi = (Vd[2 * k2 + 1][j >> 1] >> sh) & 0xffffu;
                Wd[k2] = lo | (hi << 16);
            }
            uint4 wv; wv.x = Wd[0]; wv.y = Wd[1]; wv.z = Wd[2]; wv.w = Wd[3];
            *(uint4*)&B_s[(nb + j) * 144 + slot_w * 8] = wv;
        }
    }
    __syncthreads();

    floatx4 acc[4][8];
    #pragma unroll
    for (int i = 0; i < 4; ++i)
        #pragma unroll
        for (int j = 0; j < 8; ++j) acc[i][j] = (floatx4)0.f;

    #pragma unroll
    for (int kk = 0; kk < 4; ++kk) {               // K = 128 = 4 x 32
        short8 bb[8];
        #pragma unroll
        for (int jt = 0; jt < 8; ++jt) {
            int nl = jt * 16 + r;
            int slot_r = (kk * 4 + q) ^ (nl >> 3);
            bb[jt] = *(const short8*)&B_s[nl * 144 + slot_r * 8];
        }
        #pragma unroll
        for (int it = 0; it < 4; ++it)
            #pragma unroll
            for (int jt = 0; jt < 8; ++jt)
                acc[it][jt] = __builtin_amdgcn_mfma_f32_16x16x32_bf16(
                    a[it][kk], bb[jt], acc[it][jt], 0, 0, 0);
    }

    __syncthreads();                               // B_s dead -> reuse as E
    float* Ew = (float*)smem + w * 2112;           // wave-private 16 x 132 f32
    const int n_base = nt * 128;
    float* zb = z + (size_t)b * 256 * 3136;
    #pragma unroll
    for (int it = 0; it < 4; ++it) {
        int o0 = w * 64 + it * 16 + q * 4;
        floatx4 bias = *(const floatx4*)(bias2 + o0);
        #pragma unroll
        for (int jt = 0; jt < 8; ++jt) {
            int n = jt * 16 + r;
            #pragma unroll
            for (int j = 0; j < 4; ++j)
                Ew[(q * 4 + j) * 132 + n] = fmaxf(acc[it][jt][j] + bias[j], 0.f);
        }
        // cross-lane within wave through LDS: explicit fence as insurance
        asm volatile("s_waitcnt lgkmcnt(0)" ::: "memory");
        __builtin_amdgcn_sched_barrier(0);
        #pragma unroll
        for (int s = 0; s < 8; ++s) {
            int chunk = s * 64 + lane;             // wave-private rows only
            int rho = chunk >> 5, n4 = (chunk & 31) * 4;
            if (n_base + n4 < 3136) {
                floatx4 v = *(const floatx4*)&Ew[rho * 132 + n4];
                int o = w * 64 + it * 16 + rho;
                __builtin_nontemporal_store(v,
                    (floatx4*)(zb + (size_t)o * 3136 + n_base + n4));
            }
        }
    }
}

extern "C" void kernel_launch(void* const* d_in, const int* in_sizes, int n_in,
                              void* d_out, int out_size, void* d_ws, size_t ws_size,
                              hipStream_t stream) {
    const float* x    = (const float*)d_in[0];
    const float* dw_w = (const float*)d_in[1];
    const float* dw_b = (const float*)d_in[2];
    const float* g1   = (const float*)d_in[3];
    const float* b1   = (const float*)d_in[4];
    const float* m1   = (const float*)d_in[5];
    const float* v1   = (const float*)d_in[6];
    const float* pw_w = (const float*)d_in[7];
    const float* pw_b = (const float*)d_in[8];
    const float* g2   = (const float*)d_in[9];
    const float* b2   = (const float*)d_in[10];
    const float* m2   = (const float*)d_in[11];
    const float* v2   = (const float*)d_in[12];
    float* z = (float*)d_out;

    // ws layout: y (bf16) 51,380,224 B | w_bf 65,536 B | bias2 1,024 B
    const size_t YB = 51380224;
    unsigned short* y_ws = (unsigned short*)d_ws;
    unsigned short* w_bf = (unsigned short*)((char*)d_ws + YB);
    float* bias2         = (float*)((char*)d_ws + YB + 65536);

    hipLaunchKernelGGL(k_dw, dim3(128, 64), dim3(256), 0, stream,
                       x, dw_w, dw_b, g1, b1, m1, v1,
                       pw_w, pw_b, g2, b2, m2, v2, y_ws, w_bf, bias2);
    hipLaunchKernelGGL(k_pw, dim3(25, 64), dim3(256), 0, stream,
                       y_ws, w_bf, bias2, z);
}